// Round 11
// baseline (415.018 us; speedup 1.0000x reference)
//
#include <hip/hip_runtime.h>
#include <math.h>

// Problem constants
#define Bsz  4096
#define Tlen 512
#define NE   30
#define NIN  5
#define HD10 10
#define B10  (Bsz*HD10)   // per-head plane: 40960 floats

typedef _Float16 h2v  __attribute__((ext_vector_type(2)));
typedef _Float16 f16x8 __attribute__((ext_vector_type(8)));
typedef float    f32x4 __attribute__((ext_vector_type(4)));

__device__ __forceinline__ float fexp2(float x){ return __builtin_amdgcn_exp2f(x); }
__device__ __forceinline__ float frcp (float x){ return __builtin_amdgcn_rcpf(x); }
#define L2E 1.4426950408889634f

__device__ __forceinline__ void loadarr32(float arr[32], const float* bufrow){
  const float4* p4 = (const float4*)bufrow;
  #pragma unroll
  for (int q4=0;q4<8;q4++){ float4 vv=p4[q4]; arr[4*q4]=vv.x; arr[4*q4+1]=vv.y; arr[4*q4+2]=vv.z; arr[4*q4+3]=vv.w; }
}

// ---------------------------------------------------------------------------
// Kernel 1 (MFMA LSTM) -- R8 structure, UNCHANGED (266us known-good).
// NOTE for future rounds: pipe arithmetic says the LSTM floor is the
// TRANSCENDENTAL pipe: 4096x512x30 dims x 10 trans (4 sigmoid + tanh, each
// exp2+rcp) = 6.3G lane-trans / (16 lane/cyc/SIMD x 1024) ~= 160us chip-wide.
// 266us = ~60% of that floor (VALUBusy 26% ~= trans share of the 1250cyc
// step wall). The only way past it is polynomial gates on the FMA pipe.
// ---------------------------------------------------------------------------
extern "C" __global__ void __launch_bounds__(128)
lstm_k(const float* __restrict__ input, const float* __restrict__ w_ih,
       const float* __restrict__ w_hh, const float* __restrict__ b_ih,
       const float* __restrict__ b_hh, const float* __restrict__ in_proj_w,
       const float* __restrict__ in_proj_b,
       float* __restrict__ qo, float* __restrict__ ko, float* __restrict__ vo,
       float* __restrict__ ho)
{
  __shared__ __align__(16) _Float16 hbufh[2*16*40];  // [parity][n][k] 2560 B
  __shared__ __align__(16) float    xstf[16*390];    // x: [n][t][6pad] stride 390 dw
  const int tidb = threadIdx.x;
  const int wave = tidb >> 6;
  const int lane = tidb & 63;
  const int n    = lane & 15;        // batch within group (B-frag/D col)
  const int quad = lane >> 4;
  const int b0   = blockIdx.x * 16;

  const int mrow = 16*wave + n;            // dim within gate for A rows
  const bool rv  = (mrow < NE);
  f16x8 ah[4], ax[4];
  f32x4 bi[4];
  #pragma unroll
  for (int G=0; G<4; ++G){
    const float sG = (G==2) ? (-2.f*L2E) : (-L2E);   // g gate: tanh via 2sig(2x)-1
    const int grow = rv ? (NE*G + mrow) : 0;
    #pragma unroll
    for (int j=0;j<8;++j){
      const int k = quad*8 + j;
      ah[G][j] = (rv && k < NE) ? (_Float16)(sG*w_hh[grow*NE + k]) : (_Float16)0;
      ax[G][j] = (rv && quad==0 && j < NIN) ? (_Float16)(sG*w_ih[grow*NIN + j]) : (_Float16)0;
    }
    #pragma unroll
    for (int r=0;r<4;++r){
      const int d = 16*wave + quad*4 + r;  // D row -> dim
      const int gr = (d < NE) ? (NE*G + d) : 0;
      bi[G][r] = (d < NE) ? sG*(b_ih[gr] + b_hh[gr]) : 0.f;
    }
  }
  for (int i=tidb; i<640; i+=128) ((float*)hbufh)[i] = 0.f;

  float c0=0.f,c1=0.f,c2=0.f,c3=0.f;
  float h0f=0.f,h1f=0.f,h2f=0.f,h3f=0.f;
  const int hb = n*40 + quad*8;            // bh read offset (halves)
  const int hw = n*40 + 16*wave + 4*quad;  // h write offset (halves)
  const bool q0 = (quad == 0);
  const f16x8 zf8 = (f16x8)(_Float16)0;
  const float2* x2p = (const float2*)xstf;
  const int xb2 = n*195;                   // float2 index base for this batch

  for (int tc = 0; tc < Tlen; tc += 64) {
    __syncthreads();
    for (int i = tidb; i < 5120; i += 128){
      const int nn = i/320, e = i%320;
      xstf[nn*390 + (e/5)*6 + (e%5)] =
        input[(size_t)(b0+nn)*(Tlen*NIN) + tc*5 + e];
    }
    __syncthreads();
    #pragma unroll 1
    for (int tl2 = 0; tl2 < 32; ++tl2) {
      const int base0 = xb2 + (2*tl2)*3;
      const float2 a0 = x2p[base0],   a1 = x2p[base0+1], a2 = x2p[base0+2];
      const float2 b1 = x2p[base0+3], b2 = x2p[base0+4], b3 = x2p[base0+5];
      #pragma unroll
      for (int par=0; par<2; ++par) {
        const _Float16* rbuf = hbufh + par*640;
        _Float16*       wbuf = hbufh + (par^1)*640;
        const f16x8 bh = *(const f16x8*)(rbuf + hb);
        const float xv0 = par ? b1.x : a0.x;
        const float xv1 = par ? b1.y : a0.y;
        const float xv2 = par ? b2.x : a1.x;
        const float xv3 = par ? b2.y : a1.y;
        const float xv4 = par ? b3.x : a2.x;
        union { f16x8 v; h2v h[4]; } U;
        U.h[0].x=(_Float16)xv0; U.h[0].y=(_Float16)xv1;
        U.h[1].x=(_Float16)xv2; U.h[1].y=(_Float16)xv3;
        U.h[2].x=(_Float16)xv4; U.h[2].y=(_Float16)0;
        U.h[3]=(h2v)0;
        const f16x8 bx = q0 ? U.v : zf8;
        f32x4 Ci = __builtin_amdgcn_mfma_f32_16x16x32_f16(ax[0], bx, bi[0], 0,0,0);
        f32x4 Cf = __builtin_amdgcn_mfma_f32_16x16x32_f16(ax[1], bx, bi[1], 0,0,0);
        f32x4 Cg = __builtin_amdgcn_mfma_f32_16x16x32_f16(ax[2], bx, bi[2], 0,0,0);
        f32x4 Co = __builtin_amdgcn_mfma_f32_16x16x32_f16(ax[3], bx, bi[3], 0,0,0);
        Ci = __builtin_amdgcn_mfma_f32_16x16x32_f16(ah[0], bh, Ci, 0,0,0);
        Cf = __builtin_amdgcn_mfma_f32_16x16x32_f16(ah[1], bh, Cf, 0,0,0);
        Cg = __builtin_amdgcn_mfma_f32_16x16x32_f16(ah[2], bh, Cg, 0,0,0);
        Co = __builtin_amdgcn_mfma_f32_16x16x32_f16(ah[3], bh, Co, 0,0,0);
        {
          const float iv = frcp(1.f + fexp2(Ci[0]));
          const float fv = frcp(1.f + fexp2(Cf[0]));
          const float gv = fmaf(2.f, frcp(1.f + fexp2(Cg[0])), -1.f);
          const float ov = frcp(1.f + fexp2(Co[0]));
          c0 = fmaf(fv, c0, iv*gv);
          const float r2 = frcp(1.f + fexp2((2.f*L2E)*c0));
          h0f = ov * fmaf(-2.f, r2, 1.f);
        }
        {
          const float iv = frcp(1.f + fexp2(Ci[1]));
          const float fv = frcp(1.f + fexp2(Cf[1]));
          const float gv = fmaf(2.f, frcp(1.f + fexp2(Cg[1])), -1.f);
          const float ov = frcp(1.f + fexp2(Co[1]));
          c1 = fmaf(fv, c1, iv*gv);
          const float r2 = frcp(1.f + fexp2((2.f*L2E)*c1));
          h1f = ov * fmaf(-2.f, r2, 1.f);
        }
        {
          const float iv = frcp(1.f + fexp2(Ci[2]));
          const float fv = frcp(1.f + fexp2(Cf[2]));
          const float gv = fmaf(2.f, frcp(1.f + fexp2(Cg[2])), -1.f);
          const float ov = frcp(1.f + fexp2(Co[2]));
          c2 = fmaf(fv, c2, iv*gv);
          const float r2 = frcp(1.f + fexp2((2.f*L2E)*c2));
          h2f = ov * fmaf(-2.f, r2, 1.f);
        }
        {
          const float iv = frcp(1.f + fexp2(Ci[3]));
          const float fv = frcp(1.f + fexp2(Cf[3]));
          const float gv = fmaf(2.f, frcp(1.f + fexp2(Cg[3])), -1.f);
          const float ov = frcp(1.f + fexp2(Co[3]));
          c3 = fmaf(fv, c3, iv*gv);
          const float r2 = frcp(1.f + fexp2((2.f*L2E)*c3));
          h3f = ov * fmaf(-2.f, r2, 1.f);
        }
        h2v q01, q23;
        q01.x=(_Float16)h0f; q01.y=(_Float16)h1f;
        q23.x=(_Float16)h2f; q23.y=(_Float16)h3f;
        float2 wv;
        wv.x = __builtin_bit_cast(float, q01);
        wv.y = __builtin_bit_cast(float, q23);
        *(float2*)(wbuf + hw) = wv;
        __syncthreads();
      }
    }
  }

  float* hf = xstf;            // [16][36]
  float* cf = xstf + 16*36;
  __syncthreads();
  {
    const int d0 = 16*wave + 4*quad;
    float4 hv4; hv4.x=h0f; hv4.y=h1f; hv4.z=h2f; hv4.w=h3f;
    float4 cv4; cv4.x=c0;  cv4.y=c1;  cv4.z=c2;  cv4.w=c3;
    *(float4*)(&hf[n*36 + d0]) = hv4;
    *(float4*)(&cf[n*36 + d0]) = cv4;
  }
  __syncthreads();
  for (int i = tidb; i < 16*NE; i += 128){
    const int nn = i/NE, d = i%NE;
    ho[(size_t)(b0+nn)*NE + d] = hf[nn*36 + d];
  }
  const float QS = 0.31622776601683794f;     // 1/sqrt(10)
  for (int i = tidb; i < 90*16; i += 128){
    const int o  = i % 90;
    const int nn = i / 90;
    const float* wrow = in_proj_w + o*NE;
    const float* src  = (o < NE) ? &hf[nn*36] : &cf[nn*36];
    float acc = in_proj_b[o];
    #pragma unroll
    for (int k2=0;k2<NE;k2++) acc = fmaf(wrow[k2], src[k2], acc);
    const int b = b0 + nn;
    if (o < 30)      { qo[(o/10)*B10 + b*10 + (o%10)] = acc * QS; }
    else if (o < 60) { const int u=o-30; ko[(u/10)*B10 + b*10 + (u%10)] = acc; }
    else             { const int u=o-60; vo[(u/10)*B10 + b*10 + (u%10)] = acc; }
  }
}

// ---------------------------------------------------------------------------
// Kernel 2 (R11: query-tiled QT=4): flash attention partials.
// ROOT-CAUSE of the stubborn ~130-155us gap (5 attn variants): every wave
// re-read every key row individually -- 10 broadcast loads/key/wave on the
// shared per-CU LDS/VMEM pipe ~= 75-90us chip-wide, plus per-key softmax
// overhead paid once PER QUERY. Fix: each thread owns 4 queries, so per-key
// loads + corr overhead amortize 4x and FMA/wave-key quadruples.
// K/V staged in LDS rows padded to 16 floats (b128-aligned: 2xb128+1xb64).
// Live set ~130 VGPR -> __launch_bounds__(256,2) (256 budget, no demotion).
// grid (4 qblocks, 3 heads, NS<=32) -> up to 1536 waves.
// ---------------------------------------------------------------------------
extern "C" __global__ void __launch_bounds__(256, 2)
attn_part(const float* __restrict__ q, const float* __restrict__ k,
          const float* __restrict__ v, float* __restrict__ part, int nkeys)
{
  __shared__ __align__(16) float kst[64*16];
  __shared__ __align__(16) float vst[64*16];
  const int t    = threadIdx.x;
  const int head = blockIdx.y;
  const int ks   = blockIdx.z;
  const int qb   = blockIdx.x * 1024;
  const float* kh = k + (size_t)head*B10;
  const float* vh = v + (size_t)head*B10;
  float qreg[4][10];
  #pragma unroll
  for (int j=0;j<4;j++){
    const float2* qp = (const float2*)(q + (size_t)head*B10 + (size_t)(qb + j*256 + t)*10);
    #pragma unroll
    for (int i=0;i<5;i++){ float2 t2=qp[i]; qreg[j][2*i]=t2.x; qreg[j][2*i+1]=t2.y; }
  }
  float m[4], l[4], acc[4][10];
  #pragma unroll
  for (int j=0;j<4;j++){
    m[j] = -INFINITY; l[j] = 0.f;
    #pragma unroll
    for (int d=0;d<10;d++) acc[j][d]=0.f;
  }

  const int k0 = ks * nkeys;
  #pragma unroll 1
  for (int ti=0; ti<nkeys; ti+=64){
    __syncthreads();                 // previous tile's reads complete
    for (int i=t; i<640; i+=256){
      const int kk = i/10, e = i%10;
      kst[kk*16 + e] = kh[(size_t)(k0+ti)*10 + i];
      vst[kk*16 + e] = vh[(size_t)(k0+ti)*10 + i];
    }
    __syncthreads();                 // staging visible
    #pragma unroll 1
    for (int c4=0; c4<64; c4+=4){
      float s[4][4];
      #pragma unroll
      for (int u=0;u<4;u++){
        const float4 ka = *(const float4*)(kst + (c4+u)*16);
        const float4 kb = *(const float4*)(kst + (c4+u)*16 + 4);
        const float2 kc = *(const float2*)(kst + (c4+u)*16 + 8);
        #pragma unroll
        for (int j=0;j<4;j++){
          float sv;
          sv = qreg[j][0]*ka.x;
          sv = fmaf(qreg[j][1], ka.y, sv);
          sv = fmaf(qreg[j][2], ka.z, sv);
          sv = fmaf(qreg[j][3], ka.w, sv);
          sv = fmaf(qreg[j][4], kb.x, sv);
          sv = fmaf(qreg[j][5], kb.y, sv);
          sv = fmaf(qreg[j][6], kb.z, sv);
          sv = fmaf(qreg[j][7], kb.w, sv);
          sv = fmaf(qreg[j][8], kc.x, sv);
          sv = fmaf(qreg[j][9], kc.y, sv);
          s[j][u] = sv;
        }
      }
      #pragma unroll
      for (int j=0;j<4;j++){
        const float mc = fmaxf(fmaxf(s[j][0],s[j][1]), fmaxf(s[j][2],s[j][3]));
        const float mn = fmaxf(m[j], mc);
        const float corr = fexp2(L2E*(m[j]-mn));   // -inf first -> 0
        l[j] *= corr;
        #pragma unroll
        for (int d=0;d<10;d++) acc[j][d] *= corr;
        m[j] = mn;
      }
      #pragma unroll
      for (int u=0;u<4;u++){
        const float4 va = *(const float4*)(vst + (c4+u)*16);
        const float4 vb = *(const float4*)(vst + (c4+u)*16 + 4);
        const float2 vc = *(const float2*)(vst + (c4+u)*16 + 8);
        #pragma unroll
        for (int j=0;j<4;j++){
          const float p = fexp2(L2E*(s[j][u]-m[j]));
          l[j] += p;
          acc[j][0] = fmaf(p, va.x, acc[j][0]);
          acc[j][1] = fmaf(p, va.y, acc[j][1]);
          acc[j][2] = fmaf(p, va.z, acc[j][2]);
          acc[j][3] = fmaf(p, va.w, acc[j][3]);
          acc[j][4] = fmaf(p, vb.x, acc[j][4]);
          acc[j][5] = fmaf(p, vb.y, acc[j][5]);
          acc[j][6] = fmaf(p, vb.z, acc[j][6]);
          acc[j][7] = fmaf(p, vb.w, acc[j][7]);
          acc[j][8] = fmaf(p, vc.x, acc[j][8]);
          acc[j][9] = fmaf(p, vc.y, acc[j][9]);
        }
      }
    }
  }
  #pragma unroll
  for (int j=0;j<4;j++){
    const int qr = qb + j*256 + t;
    float* pp = part + ((size_t)(head*Bsz + qr)*gridDim.z + ks)*12;
    pp[0]=m[j]; pp[1]=l[j];
    #pragma unroll
    for (int d=0;d<10;d++) pp[2+d]=acc[j][d];
  }
}

// ---------------------------------------------------------------------------
// Kernel 3 (R10 LDS-weights version, unchanged): merge + out_proj + LN +
// MLP(exact GELU) + LN + head. One wave per row.
// ---------------------------------------------------------------------------
extern "C" __global__ void __launch_bounds__(256)
tail_k(const float* __restrict__ part, int ns, const float* __restrict__ hn,
       const float* __restrict__ out_proj_w, const float* __restrict__ out_proj_b,
       const float* __restrict__ fc1_w, const float* __restrict__ fc1_b,
       const float* __restrict__ fc2_w, const float* __restrict__ fc2_b,
       const float* __restrict__ ln_g, const float* __restrict__ ln_b,
       const float* __restrict__ out_w, const float* __restrict__ out_b,
       float* __restrict__ out)
{
  __shared__ __align__(16) float buf[4][32];
  __shared__ float wl[2880];
  const int tidb = threadIdx.x;
  for (int i=tidb;i<900;i+=256) wl[i]       = out_proj_w[i];
  for (int i=tidb;i<900;i+=256) wl[900+i]   = fc1_w[i];
  for (int i=tidb;i<900;i+=256) wl[1800+i]  = fc2_w[i];
  if (tidb < 90) wl[2700+tidb] = out_w[tidb];
  const int wave = tidb >> 6;
  const int lane = tidb & 63;
  const int b = blockIdx.x*4 + wave;
  const bool act = (lane < NE);
  if (lane < 32) buf[wave][lane] = 0.f;
  __syncthreads();
  if (act) {
    const int head = lane/10, dd = lane%10;
    const float* p = part + ((size_t)(head*Bsz + b)*ns)*12;
    float M = -INFINITY, L = 0.f, O = 0.f;
    for (int i=0;i<ns;i++){
      const float mi = p[i*12], li = p[i*12+1], ai = p[i*12+2+dd];
      const float Mn = fmaxf(M, mi);
      const float cw = fexp2(L2E*(M - Mn));
      const float wi = fexp2(L2E*(mi - Mn));
      L = fmaf(li, wi, L*cw);
      O = fmaf(ai, wi, O*cw);
      M = Mn;
    }
    buf[wave][lane] = O / L;
  }
  __builtin_amdgcn_wave_barrier();
  float arr[32];
  loadarr32(arr, &buf[wave][0]);
  const float hv = act ? hn[b*NE+lane] : 0.f;
  float x = 0.f;
  if (act) {
    float a = out_proj_b[lane];
    #pragma unroll
    for (int k2=0;k2<NE;k2++) a = fmaf(wl[lane*NE+k2], arr[k2], a);
    x = a + hv;                       // attn_out + h_n
  }
  __builtin_amdgcn_wave_barrier();
  if (act) buf[wave][lane] = x;
  __builtin_amdgcn_wave_barrier();
  loadarr32(arr, &buf[wave][0]);
  float s1=0.f, s2=0.f;
  #pragma unroll
  for (int k2=0;k2<32;k2++){ s1+=arr[k2]; s2=fmaf(arr[k2],arr[k2],s2); }
  float mu = s1*(1.f/30.f);
  float var = s2*(1.f/30.f) - mu*mu;
  float rs = rsqrtf(var + 1e-5f);
  float x1 = 0.f;
  if (act) x1 = fmaf((x-mu)*rs, ln_g[lane], ln_b[lane]);
  __builtin_amdgcn_wave_barrier();
  if (act) buf[wave][lane] = x1;
  __builtin_amdgcn_wave_barrier();
  loadarr32(arr, &buf[wave][0]);
  float gv = 0.f;
  if (act) {
    float a = fc1_b[lane];
    #pragma unroll
    for (int k2=0;k2<NE;k2++) a = fmaf(wl[900+lane*NE+k2], arr[k2], a);
    gv = 0.5f*a*(1.f + erff(a*0.70710678118654752f));
  }
  __builtin_amdgcn_wave_barrier();
  if (act) buf[wave][lane] = gv;
  __builtin_amdgcn_wave_barrier();
  loadarr32(arr, &buf[wave][0]);
  float y = 0.f;
  if (act) {
    float a = fc2_b[lane];
    #pragma unroll
    for (int k2=0;k2<NE;k2++) a = fmaf(wl[1800+lane*NE+k2], arr[k2], a);
    y = x1 + a;                        // residual x1 + fc
  }
  __builtin_amdgcn_wave_barrier();
  if (act) buf[wave][lane] = y;
  __builtin_amdgcn_wave_barrier();
  loadarr32(arr, &buf[wave][0]);
  s1=0.f; s2=0.f;
  #pragma unroll
  for (int k2=0;k2<32;k2++){ s1+=arr[k2]; s2=fmaf(arr[k2],arr[k2],s2); }
  mu = s1*(1.f/30.f);
  var = s2*(1.f/30.f) - mu*mu;
  rs = rsqrtf(var + 1e-5f);
  float x2 = 0.f;
  if (act) x2 = fmaf((y-mu)*rs, ln_g[lane], ln_b[lane]);
  __builtin_amdgcn_wave_barrier();
  if (act) buf[wave][lane] = x2;
  __builtin_amdgcn_wave_barrier();
  loadarr32(arr, &buf[wave][0]);
  if (lane < 3) {
    float a = out_b[lane];
    #pragma unroll
    for (int k2=0;k2<NE;k2++) a = fmaf(wl[2700+lane*NE+k2], arr[k2], a);
    out[b*3 + lane] = a;
  }
}

extern "C" void kernel_launch(void* const* d_in, const int* in_sizes, int n_in,
                              void* d_out, int out_size, void* d_ws, size_t ws_size,
                              hipStream_t stream)
{
  const float* input      = (const float*)d_in[0];
  const float* w_ih       = (const float*)d_in[1];
  const float* w_hh       = (const float*)d_in[2];
  const float* b_ih       = (const float*)d_in[3];
  const float* b_hh       = (const float*)d_in[4];
  const float* in_proj_w  = (const float*)d_in[5];
  const float* in_proj_b  = (const float*)d_in[6];
  const float* out_proj_w = (const float*)d_in[7];
  const float* out_proj_b = (const float*)d_in[8];
  const float* fc1_w      = (const float*)d_in[9];
  const float* fc1_b      = (const float*)d_in[10];
  const float* fc2_w      = (const float*)d_in[11];
  const float* fc2_b      = (const float*)d_in[12];
  const float* ln_g       = (const float*)d_in[13];
  const float* ln_b       = (const float*)d_in[14];
  const float* out_w      = (const float*)d_in[15];
  const float* out_b      = (const float*)d_in[16];

  float* ws = (float*)d_ws;
  float* qo   = ws;                 // [3][4096][10]
  float* ko   = ws + 122880;        // [3][4096][10]
  float* vo   = ws + 245760;        // [3][4096][10]
  float* hn   = ws + 368640;        // [4096][30]
  float* part = ws + 491520;        // [3][4096][NS][12]

  // NS cascade by ws capacity (deterministic: ws_size fixed -> graph-safe)
  const size_t need32 = ((size_t)491520 + (size_t)3*4096*32*12) * 4;
  const size_t need16 = ((size_t)491520 + (size_t)3*4096*16*12) * 4;
  const int NS = (ws_size >= need32) ? 32 : (ws_size >= need16) ? 16 : 8;

  lstm_k<<<Bsz/16, 128, 0, stream>>>(input, w_ih, w_hh, b_ih, b_hh,
                                     in_proj_w, in_proj_b, qo, ko, vo, hn);
  attn_part<<<dim3(4, 3, NS), 256, 0, stream>>>(qo, ko, vo, part, Bsz/NS);
  tail_k<<<Bsz/4, 256, 0, stream>>>(part, NS, hn, out_proj_w, out_proj_b,
                                    fc1_w, fc1_b, fc2_w, fc2_b,
                                    ln_g, ln_b, out_w, out_b, (float*)d_out);
}